// Round 1
// baseline (983.344 us; speedup 1.0000x reference)
//
#include <hip/hip_runtime.h>
#include <hip/hip_bf16.h>
#include <math.h>

namespace {
constexpr int B_ = 4, HQ_ = 32, HK_ = 8, G_ = 4, M_ = 16;
constexpr int N_ = 8192, D_ = 128, S_ = 256, O_ = 8, SO_ = 64;
constexpr int TN = 64;  // n-rows per block
}

// ---------------- kernel A: sketched_q = q · P  ([B*HQ][M][S], fp32) ----------------
__global__ __launch_bounds__(256) void qjl_sketch_q(const float* __restrict__ q,
                                                    const float* __restrict__ P,
                                                    float* __restrict__ sq) {
    __shared__ float qs[M_][D_];
    const int tid = threadIdx.x;
    const size_t blk = blockIdx.x;  // b*HQ + hq
    const float* qb = q + blk * (size_t)(M_ * D_);
    for (int i = tid; i < M_ * D_ / 4; i += 256)
        reinterpret_cast<float4*>(&qs[0][0])[i] = reinterpret_cast<const float4*>(qb)[i];
    __syncthreads();
    float acc[M_];
#pragma unroll
    for (int m = 0; m < M_; ++m) acc[m] = 0.f;
    const int s = tid;  // 256 threads == 256 s columns
    for (int d = 0; d < D_; ++d) {
        const float pv = P[d * S_ + s];
#pragma unroll
        for (int m = 0; m < M_; ++m) acc[m] = fmaf(qs[m][d], pv, acc[m]);
    }
    float* ob = sq + blk * (size_t)(M_ * S_);
#pragma unroll
    for (int m = 0; m < M_; ++m) ob[m * S_ + s] = acc[m];
}

// ---------------- kernel B: main ----------------
// grid (N/TN, HK, B), block 256 (4 waves). Wave w owns rows [16w,16w+16) for the
// sign matmul and head g=w for the output phase; lane l owns s in {l,l+64,l+128,l+192}.
__global__ __launch_bounds__(256) void qjl_main(const float* __restrict__ data,
                                                const float* __restrict__ q,
                                                const float* __restrict__ P,
                                                const int* __restrict__ oidx,
                                                const float* __restrict__ sq,
                                                float* __restrict__ out) {
    __shared__ float sdata[TN][D_];                // 32 KB, outliers zeroed in place
    __shared__ float qs[G_][M_][D_];               // 32 KB
    __shared__ float pch[4][S_];                   // 4 KB P chunk (4 d-rows)
    __shared__ float svals[TN][O_];                // original outlier values
    __shared__ int   sidxs[TN][O_];                // dedup'd indices (-1 = dup slot)
    __shared__ float su[TN][O_];                   // u_j per row
    __shared__ float sfull[TN];                    // full row sum-of-squares
    __shared__ float snin[TN];                     // c_in  * ||k_in||
    __shared__ float snout[TN];                    // c_out * ||k_out||
    __shared__ unsigned long long sbits[TN][4];    // sign_in bitmasks

    const int tid = threadIdx.x;
    const int lane = tid & 63;
    const int wv = tid >> 6;
    const int nt = blockIdx.x, hk = blockIdx.y, b = blockIdx.z;
    const int n0 = nt * TN;

    // ---- phase 0: load data tile (+ per-row sumsq) and q tile ----
    {
        const int r = tid >> 2;  // row 0..63
        const int c = tid & 3;
        const float* drow = data + ((size_t)(b * HK_ + hk) * N_ + n0 + r) * D_;
        float ssq = 0.f;
#pragma unroll
        for (int k = 0; k < 8; ++k) {
            const int f = c + 4 * k;  // float4 index within row (lanes 0..3 cover 64B)
            float4 v = reinterpret_cast<const float4*>(drow)[f];
            reinterpret_cast<float4*>(&sdata[r][0])[f] = v;
            ssq += v.x * v.x + v.y * v.y + v.z * v.z + v.w * v.w;
        }
        ssq += __shfl_xor(ssq, 1);
        ssq += __shfl_xor(ssq, 2);
        if (c == 0) sfull[r] = ssq;

        const float* qb = q + (size_t)(b * HQ_ + hk * G_) * (M_ * D_);
        for (int i = tid; i < G_ * M_ * D_ / 4; i += 256)
            reinterpret_cast<float4*>(&qs[0][0][0])[i] = reinterpret_cast<const float4*>(qb)[i];
    }
    __syncthreads();

    // ---- phase A: dedup outliers, record values, zero them in sdata, norms ----
    if (tid < TN) {
        const int n = tid;
        const int* ob = oidx + ((size_t)(b * HK_ + hk) * N_ + n0 + n) * O_;
        int id[O_];
        int4 i0 = reinterpret_cast<const int4*>(ob)[0];
        int4 i1 = reinterpret_cast<const int4*>(ob)[1];
        id[0] = i0.x; id[1] = i0.y; id[2] = i0.z; id[3] = i0.w;
        id[4] = i1.x; id[5] = i1.y; id[6] = i1.z; id[7] = i1.w;
        float so2 = 0.f;
#pragma unroll
        for (int j = 0; j < O_; ++j) {
            bool dup = false;
#pragma unroll
            for (int jj = 0; jj < O_; ++jj)
                if (jj < j) dup = dup || (id[jj] == id[j]);
            if (!dup) {
                const float v = sdata[n][id[j]];
                svals[n][j] = v;
                sidxs[n][j] = id[j];
                so2 = fmaf(v, v, so2);
                sdata[n][id[j]] = 0.f;  // sdata now holds k_in exactly
            } else {
                svals[n][j] = 0.f;
                sidxs[n][j] = -1;
            }
        }
        const float CIN = (float)(1.2533141373155003 / 256.0);   // sqrt(pi/2)/S
        const float COUT = (float)(1.2533141373155003 / 64.0);   // sqrt(pi/2)/SO
        snin[n] = CIN * sqrtf(fmaxf(sfull[n] - so2, 0.f));
        snout[n] = COUT * sqrtf(so2);
    }
    __syncthreads();

    // ---- phase B: sign_out (fp64 dot) and u_j; 4 threads per row ----
    {
        const int n = tid >> 2;
        const int c = tid & 3;
        float u[O_];
        float vv[O_];
        int idc[O_];
#pragma unroll
        for (int j = 0; j < O_; ++j) {
            u[j] = 0.f;
            const int ix = sidxs[n][j];
            idc[j] = (ix >= 0) ? ix : 0;  // clamp dups; their u is never used
            vv[j] = svals[n][j];          // dups carry 0 -> no effect on cs
        }
        for (int t = c * 16; t < c * 16 + 16; ++t) {
            double cs = 0.0;
#pragma unroll
            for (int j = 0; j < O_; ++j)
                cs = fma((double)vv[j], (double)P[idc[j] * S_ + t], cs);
            const float sg = (cs > 0.0) ? 1.f : ((cs < 0.0) ? -1.f : 0.f);
#pragma unroll
            for (int j = 0; j < O_; ++j)
                u[j] = fmaf(sg, P[idc[j] * S_ + t], u[j]);
        }
#pragma unroll
        for (int j = 0; j < O_; ++j) {
            u[j] += __shfl_xor(u[j], 1);
            u[j] += __shfl_xor(u[j], 2);
        }
        if (c == 0) {
#pragma unroll
            for (int j = 0; j < O_; ++j) su[n][j] = u[j];
        }
    }
    // (phase C's barriers order su/sdata writes before phase D reads)

    // ---- phase C: G = k_in · P, fp64 accumulators; pack sign bits ----
    {
        double acc[16][4];
#pragma unroll
        for (int r = 0; r < 16; ++r)
#pragma unroll
            for (int k = 0; k < 4; ++k) acc[r][k] = 0.0;

        for (int dc = 0; dc < D_; dc += 4) {
            __syncthreads();
            reinterpret_cast<float4*>(&pch[0][0])[tid] =
                reinterpret_cast<const float4*>(P + dc * S_)[tid];  // 4 rows x 256
            __syncthreads();
            double pv[4][4];
#pragma unroll
            for (int i = 0; i < 4; ++i)
#pragma unroll
                for (int k = 0; k < 4; ++k) pv[i][k] = (double)pch[i][64 * k + lane];
#pragma unroll
            for (int r = 0; r < 16; ++r) {
                const float4 dv = *reinterpret_cast<const float4*>(&sdata[wv * 16 + r][dc]);
                const double dx = dv.x, dy = dv.y, dz = dv.z, dw = dv.w;
#pragma unroll
                for (int k = 0; k < 4; ++k) {
                    double a = acc[r][k];
                    a = fma(dx, pv[0][k], a);
                    a = fma(dy, pv[1][k], a);
                    a = fma(dz, pv[2][k], a);
                    a = fma(dw, pv[3][k], a);
                    acc[r][k] = a;
                }
            }
        }
#pragma unroll
        for (int r = 0; r < 16; ++r) {
            unsigned long long b0 = __ballot(acc[r][0] > 0.0);
            unsigned long long b1 = __ballot(acc[r][1] > 0.0);
            unsigned long long b2 = __ballot(acc[r][2] > 0.0);
            unsigned long long b3 = __ballot(acc[r][3] > 0.0);
            if (lane == 0) {
                sbits[wv * 16 + r][0] = b0;
                sbits[wv * 16 + r][1] = b1;
                sbits[wv * 16 + r][2] = b2;
                sbits[wv * 16 + r][3] = b3;
            }
        }
    }
    __syncthreads();

    // ---- phase D: part1 (bit-signed sum of sq) + part2 (sparse outlier dot) + store ----
    {
        const int n = lane;           // row within tile
        const int hq = hk * G_ + wv;  // wave owns one head of the group
        float accO[M_];
#pragma unroll
        for (int m = 0; m < M_; ++m) accO[m] = 0.f;
        const float cno = snout[n];
#pragma unroll
        for (int j = 0; j < O_; ++j) {
            const int ix = sidxs[n][j];
            const int ixc = (ix >= 0) ? ix : 0;
            const float uj = (ix >= 0) ? su[n][j] * cno : 0.f;
#pragma unroll
            for (int m = 0; m < M_; ++m)
                accO[m] = fmaf(uj, qs[wv][m][ixc], accO[m]);
        }

        unsigned long long bw[4];
#pragma unroll
        for (int k = 0; k < 4; ++k) bw[k] = sbits[n][k];

        const float* sqb = sq + (size_t)(b * HQ_ + hq) * (M_ * S_);
        float accI[M_];
#pragma unroll
        for (int m = 0; m < M_; ++m) accI[m] = 0.f;
        for (int k = 0; k < 4; ++k) {
            const unsigned long long w64 = bw[k];
            for (int sb = 0; sb < 64; ++sb) {
                const unsigned flip = (((unsigned)(w64 >> sb)) & 1u) ^ 1u;  // bit=1 -> +
                const unsigned msk = flip << 31;
                const float* sp = sqb + k * 64 + sb;  // wave-uniform address
#pragma unroll
                for (int m = 0; m < M_; ++m) {
                    const float v = sp[m * S_];
                    accI[m] += __uint_as_float(__float_as_uint(v) ^ msk);
                }
            }
        }

        const float cni = snin[n];
        float* ob = out + ((size_t)(b * HQ_ + hq) * N_ + (n0 + n)) * M_;
        float res[M_];
#pragma unroll
        for (int m = 0; m < M_; ++m) res[m] = fmaf(accI[m], cni, accO[m]);
#pragma unroll
        for (int m4 = 0; m4 < M_ / 4; ++m4) {
            float4 v;
            v.x = res[4 * m4 + 0];
            v.y = res[4 * m4 + 1];
            v.z = res[4 * m4 + 2];
            v.w = res[4 * m4 + 3];
            reinterpret_cast<float4*>(ob)[m4] = v;
        }
    }
}

extern "C" void kernel_launch(void* const* d_in, const int* in_sizes, int n_in,
                              void* d_out, int out_size, void* d_ws, size_t ws_size,
                              hipStream_t stream) {
    const float* query = (const float*)d_in[0];  // [B][HQ][M][D]
    const float* data  = (const float*)d_in[1];  // [B][HK][N][D]
    const float* proj  = (const float*)d_in[2];  // [D][S]
    const int*   oidx  = (const int*)d_in[3];    // [B][HK][N][O]
    // d_in[4] = dim_outlier scalar (=64), baked in as SO_

    float* out = (float*)d_out;                  // [B][HQ][N][M]
    float* sq = (float*)d_ws;                    // B*HQ*M*S floats = 2 MB scratch

    qjl_sketch_q<<<dim3(B_ * HQ_), dim3(256), 0, stream>>>(query, proj, sq);
    qjl_main<<<dim3(N_ / TN, HK_, B_), dim3(256), 0, stream>>>(data, query, proj, oidx, sq, out);
}